// Round 1
// baseline (1499.524 us; speedup 1.0000x reference)
//
#include <hip/hip_runtime.h>
#include <math.h>

#define HEADS 8
#define HC 256
#define NREL 3
#define NEG 0.2f
#define MAXDEG 128   // max in-degree; E=160k over N=10k dst -> Binomial mean 16, max ~45. 128 is hugely safe.
#define NPB 16       // nodes per block in the xw GEMM

__device__ __forceinline__ float warp32_reduce(float p) {
#pragma unroll
    for (int off = 16; off > 0; off >>= 1) p += __shfl_down(p, off, 32);
    return p;
}

// ---- CSR build -------------------------------------------------------------

__global__ void k_init(int* deg, int* fill, float* pools, float* cnt, int nnodes, int ngraph) {
    int i = blockIdx.x * blockDim.x + threadIdx.x;
    if (i < nnodes) { deg[i] = 0; fill[i] = 0; }
    if (i < ngraph * HEADS) pools[i] = 0.f;
    if (i < ngraph) cnt[i] = 0.f;
}

__global__ void k_deg(const int* __restrict__ ei, int* deg, int nedges) {
    int e = blockIdx.x * blockDim.x + threadIdx.x;
    if (e < nedges) atomicAdd(&deg[ei[nedges + e]], 1);
}

// single-block exclusive scan over nnodes (<= 1024*per) degrees -> rowptr[n+1]
__global__ void k_scan(const int* __restrict__ deg, int* rowptr, int n) {
    __shared__ int ss[1024];
    int tid = threadIdx.x;
    int per = (n + 1023) >> 10;
    int b = tid * per;
    int s = 0;
    for (int i = 0; i < per; i++) { int idx = b + i; if (idx < n) s += deg[idx]; }
    ss[tid] = s;
    __syncthreads();
    for (int off = 1; off < 1024; off <<= 1) {
        int v = (tid >= off) ? ss[tid - off] : 0;
        __syncthreads();
        ss[tid] += v;
        __syncthreads();
    }
    int run = (tid == 0) ? 0 : ss[tid - 1];
    for (int i = 0; i < per; i++) {
        int idx = b + i;
        if (idx < n) { rowptr[idx] = run; run += deg[idx]; }
    }
    if (tid == 0) rowptr[n] = ss[1023];
}

__global__ void k_scatter(const int* __restrict__ ei, const int* __restrict__ et,
                          const float* __restrict__ ea, const int* __restrict__ rowptr,
                          int* fill, int* csr_pack, float* csr_ae, int nedges) {
    int e = blockIdx.x * blockDim.x + threadIdx.x;
    if (e >= nedges) return;
    int dst = ei[nedges + e];
    int pos = atomicAdd(&fill[dst], 1);
    int slot = rowptr[dst] + pos;
    csr_pack[slot] = (ei[e] << 2) | (et[e] & 3);
    csr_ae[slot] = ea[e];
}

// ---- per-layer small precompute: wq[r,i,h]=w[r,i,:]@q[:,h], wk likewise; wee[h]=we@e ----
// grid = 3*IN blocks (one per (r,i) row), 256 threads = 8 heads x 32 lanes.
__global__ void k_prep(const float* __restrict__ w, const float* __restrict__ q,
                       const float* __restrict__ kk, const float* __restrict__ e,
                       const float* __restrict__ we, float* wq, float* wk, float* wee) {
    int tid = threadIdx.x;
    int ri = blockIdx.x;  // r*IN + i
    int h = tid >> 5, lane = tid & 31;
    const float* wrow = w + (size_t)ri * HC;
    float p = 0.f;
    for (int o = lane; o < HC; o += 32) p += wrow[o] * q[o * HEADS + h];
    p = warp32_reduce(p);
    if (lane == 0) wq[ri * HEADS + h] = p;
    p = 0.f;
    for (int o = lane; o < HC; o += 32) p += wrow[o] * kk[o * HEADS + h];
    p = warp32_reduce(p);
    if (lane == 0) wk[ri * HEADS + h] = p;
    if (blockIdx.x == 0 && tid < HEADS) {
        float s = 0.f;
        for (int o = 0; o < HC; o++) s += we[o] * e[o * HEADS + tid];
        wee[tid] = s;
    }
}

// ---- per-node qdot/kdot: qdot[n,r,h] = x[n,:] @ wq[r,:,h]  (48 outputs per node) ----
template <int IN>
__global__ void k_qk(const float* __restrict__ xin, const float* __restrict__ wq,
                     const float* __restrict__ wk, float* __restrict__ qdot,
                     float* __restrict__ kdot, int nnodes) {
    __shared__ float xrow[IN];
    int n = blockIdx.x;
    int tid = threadIdx.x;
    if (tid < IN) xrow[tid] = xin[(size_t)n * IN + tid];
    __syncthreads();
    int g = tid >> 5, lane = tid & 31;
#pragma unroll
    for (int it = 0; it < 6; ++it) {
        int idx = g + 8 * it;          // 0..47
        int qk = idx / 24, rem = idx % 24;
        int r = rem >> 3, h = rem & 7;
        const float* tab = qk ? wk : wq;
        float p = 0.f;
        for (int i = lane; i < IN; i += 32) p += xrow[i] * tab[(r * IN + i) * HEADS + h];
        p = warp32_reduce(p);
        if (lane == 0) (qk ? kdot : qdot)[n * 24 + rem] = p;
    }
}

// ---- xw[n,r,:] = x[n,:] @ w[r]  -- NPB nodes per block, 256 output cols per thread-col ----
template <int IN>
__global__ void k_xw(const float* __restrict__ xin, const float* __restrict__ w,
                     float* __restrict__ xw, int nnodes) {
    __shared__ __align__(16) float xs[NPB * IN];
    int r = blockIdx.y;
    int n0 = blockIdx.x * NPB;
    int tid = threadIdx.x;
    for (int idx = tid; idx < NPB * IN; idx += 256) {
        int nl = idx / IN, i = idx % IN;
        int n = n0 + nl;
        xs[idx] = (n < nnodes) ? xin[(size_t)n * IN + i] : 0.f;
    }
    __syncthreads();
    float acc[NPB];
#pragma unroll
    for (int j = 0; j < NPB; j++) acc[j] = 0.f;
    const float* wr = w + (size_t)r * IN * HC;
    for (int i = 0; i < IN; i += 4) {
        float w0 = wr[(i + 0) * HC + tid];
        float w1 = wr[(i + 1) * HC + tid];
        float w2 = wr[(i + 2) * HC + tid];
        float w3 = wr[(i + 3) * HC + tid];
#pragma unroll
        for (int j = 0; j < NPB; j++) {
            float4 xv = *(const float4*)&xs[j * IN + i];
            acc[j] += xv.x * w0 + xv.y * w1 + xv.z * w2 + xv.w * w3;
        }
    }
#pragma unroll
    for (int j = 0; j < NPB; j++) {
        int n = n0 + j;
        if (n < nnodes) xw[((size_t)n * NREL + r) * HC + tid] = acc[j];
    }
}

// ---- per-dst-node attention softmax + aggregation + bias + relu ----
__global__ void k_agg(const float* __restrict__ xw, const float* __restrict__ qdot,
                      const float* __restrict__ kdot, const int* __restrict__ rowptr,
                      const int* __restrict__ csr_pack, const float* __restrict__ csr_ae,
                      const float* __restrict__ wee, const float* __restrict__ bias,
                      float* __restrict__ hout, int nnodes) {
    __shared__ float salpha[MAXDEG * HEADS];
    __shared__ int spack[MAXDEG];
    __shared__ float sqd[NREL * HEADS];
    __shared__ float sinv[HEADS];
    __shared__ float swee[HEADS];
    int n = blockIdx.x;
    int tid = threadIdx.x;
    int beg = rowptr[n];
    int deg = rowptr[n + 1] - beg;
    if (deg > MAXDEG) deg = MAXDEG;
    if (tid < NREL * HEADS) sqd[tid] = qdot[n * 24 + tid];
    if (tid < HEADS) swee[tid] = wee[tid];
    __syncthreads();
    // phase 1: alpha per (edge, head), leaky-relu'd
    for (int base = 0; base < deg; base += 32) {
        int d = base + (tid >> 3);
        int h = tid & 7;
        if (d < deg) {
            int pk = csr_pack[beg + d];
            float ae = csr_ae[beg + d];
            int s = pk >> 2, t = pk & 3;
            if (h == 0) spack[d] = pk;
            float a = sqd[t * 8 + h] + kdot[s * 24 + t * 8 + h] + ae * swee[h];
            salpha[d * 8 + h] = (a > 0.f) ? a : NEG * a;
        }
    }
    __syncthreads();
    // phase 2: per-head softmax (deg ~16, serial is fine)
    if (tid < HEADS) {
        int h = tid;
        float m = -INFINITY;
        for (int d = 0; d < deg; d++) m = fmaxf(m, salpha[d * 8 + h]);
        float s = 0.f;
        for (int d = 0; d < deg; d++) {
            float ex = expf(salpha[d * 8 + h] - m);
            salpha[d * 8 + h] = ex;
            s += ex;
        }
        sinv[h] = 1.f / (s + 1e-16f);
    }
    __syncthreads();
    // phase 3: weighted aggregation of xw[src, etype] rows
    int h = tid >> 5;
    float acc = 0.f;
    for (int d = 0; d < deg; ++d) {
        int pk = spack[d];
        int s = pk >> 2, t = pk & 3;
        acc += salpha[d * 8 + h] * xw[((size_t)s * NREL + t) * HC + tid];
    }
    acc *= sinv[h];
    float v = acc + bias[tid];
    hout[(size_t)n * HC + tid] = (v > 0.f) ? v : 0.f;
}

// ---- final linear + tanh + mean-pool ----
__global__ void k_pool(const float* __restrict__ h3, const float* __restrict__ wlin,
                       const float* __restrict__ blin, const int* __restrict__ batch,
                       float* pools, float* cnt, int nnodes) {
    __shared__ float xrow[HC];
    int n = blockIdx.x, tid = threadIdx.x;
    xrow[tid] = h3[(size_t)n * HC + tid];
    __syncthreads();
    int g = tid >> 5, lane = tid & 31;
    float p = 0.f;
    for (int i = lane; i < HC; i += 32) p += xrow[i] * wlin[i * HEADS + g];
    p = warp32_reduce(p);
    int b = batch[n];
    if (lane == 0) atomicAdd(&pools[b * HEADS + g], tanhf(p + blin[g]));
    if (tid == 0) atomicAdd(&cnt[b], 1.f);
}

__global__ void k_div(const float* __restrict__ pools, const float* __restrict__ cnt,
                      float* __restrict__ out, int ngraph) {
    int t = threadIdx.x;
    if (t < ngraph * HEADS) out[t] = pools[t] / fmaxf(cnt[t >> 3], 1.f);
}

// ---------------------------------------------------------------------------

extern "C" void kernel_launch(void* const* d_in, const int* in_sizes, int n_in,
                              void* d_out, int out_size, void* d_ws, size_t ws_size,
                              hipStream_t stream) {
    const float* x    = (const float*)d_in[0];
    const int*   ei   = (const int*)d_in[1];
    const int*   et   = (const int*)d_in[2];
    const float* ea   = (const float*)d_in[3];
    const int*   batch = (const int*)d_in[4];
    const float* W[3]  = {(const float*)d_in[5],  (const float*)d_in[11], (const float*)d_in[17]};
    const float* Q[3]  = {(const float*)d_in[6],  (const float*)d_in[12], (const float*)d_in[18]};
    const float* K[3]  = {(const float*)d_in[7],  (const float*)d_in[13], (const float*)d_in[19]};
    const float* Em[3] = {(const float*)d_in[8],  (const float*)d_in[14], (const float*)d_in[20]};
    const float* WE[3] = {(const float*)d_in[9],  (const float*)d_in[15], (const float*)d_in[21]};
    const float* B[3]  = {(const float*)d_in[10], (const float*)d_in[16], (const float*)d_in[22]};
    const float* wlin = (const float*)d_in[23];
    const float* blin = (const float*)d_in[24];

    int nnodes = in_sizes[0] / 32;
    int nedges = in_sizes[2];
    int ngraph = 16;

    char* ws = (char*)d_ws;
    size_t off = 0;
    auto alloc = [&](size_t bytes) -> void* {
        void* p = ws + off;
        off = (off + bytes + 255) & ~(size_t)255;
        return p;
    };
    int*   deg      = (int*)alloc((size_t)nnodes * 4);
    int*   fill     = (int*)alloc((size_t)nnodes * 4);
    int*   rowptr   = (int*)alloc((size_t)(nnodes + 1) * 4);
    int*   csr_pack = (int*)alloc((size_t)nedges * 4);
    float* csr_ae   = (float*)alloc((size_t)nedges * 4);
    float* xw       = (float*)alloc((size_t)nnodes * NREL * HC * 4);
    float* qdot     = (float*)alloc((size_t)nnodes * NREL * HEADS * 4);
    float* kdot     = (float*)alloc((size_t)nnodes * NREL * HEADS * 4);
    float* ha       = (float*)alloc((size_t)nnodes * HC * 4);
    float* hb       = (float*)alloc((size_t)nnodes * HC * 4);
    float* wq       = (float*)alloc((size_t)NREL * HC * HEADS * 4);
    float* wk       = (float*)alloc((size_t)NREL * HC * HEADS * 4);
    float* wee      = (float*)alloc((size_t)HEADS * 4);
    float* pools    = (float*)alloc((size_t)ngraph * HEADS * 4);
    float* cnt      = (float*)alloc((size_t)ngraph * 4);
    (void)ws_size; (void)n_in; (void)out_size;

    // CSR build (edges are fixed across layers)
    k_init<<<(nnodes + 255) / 256, 256, 0, stream>>>(deg, fill, pools, cnt, nnodes, ngraph);
    k_deg<<<(nedges + 255) / 256, 256, 0, stream>>>(ei, deg, nedges);
    k_scan<<<1, 1024, 0, stream>>>(deg, rowptr, nnodes);
    k_scatter<<<(nedges + 255) / 256, 256, 0, stream>>>(ei, et, ea, rowptr, fill, csr_pack, csr_ae, nedges);

    dim3 gxw1((nnodes + NPB - 1) / NPB, NREL);

    // ---- layer 1 (IN=32): x -> ha ----
    k_prep<<<NREL * 32, 256, 0, stream>>>(W[0], Q[0], K[0], Em[0], WE[0], wq, wk, wee);
    k_qk<32><<<nnodes, 256, 0, stream>>>(x, wq, wk, qdot, kdot, nnodes);
    k_xw<32><<<gxw1, 256, 0, stream>>>(x, W[0], xw, nnodes);
    k_agg<<<nnodes, 256, 0, stream>>>(xw, qdot, kdot, rowptr, csr_pack, csr_ae, wee, B[0], ha, nnodes);

    // ---- layer 2 (IN=256): ha -> hb ----
    k_prep<<<NREL * HC, 256, 0, stream>>>(W[1], Q[1], K[1], Em[1], WE[1], wq, wk, wee);
    k_qk<HC><<<nnodes, 256, 0, stream>>>(ha, wq, wk, qdot, kdot, nnodes);
    k_xw<HC><<<gxw1, 256, 0, stream>>>(ha, W[1], xw, nnodes);
    k_agg<<<nnodes, 256, 0, stream>>>(xw, qdot, kdot, rowptr, csr_pack, csr_ae, wee, B[1], hb, nnodes);

    // ---- layer 3 (IN=256): hb -> ha ----
    k_prep<<<NREL * HC, 256, 0, stream>>>(W[2], Q[2], K[2], Em[2], WE[2], wq, wk, wee);
    k_qk<HC><<<nnodes, 256, 0, stream>>>(hb, wq, wk, qdot, kdot, nnodes);
    k_xw<HC><<<gxw1, 256, 0, stream>>>(hb, W[2], xw, nnodes);
    k_agg<<<nnodes, 256, 0, stream>>>(xw, qdot, kdot, rowptr, csr_pack, csr_ae, wee, B[2], ha, nnodes);

    // ---- head: linear + tanh + mean pool ----
    k_pool<<<nnodes, 256, 0, stream>>>(ha, wlin, blin, batch, pools, cnt, nnodes);
    k_div<<<1, 128, 0, stream>>>(pools, cnt, (float*)d_out, ngraph);
}

// Round 3
// 1276.538 us; speedup vs baseline: 1.1747x; 1.1747x over previous
//
#include <hip/hip_runtime.h>
#include <math.h>

#define HEADS 8
#define HC 256
#define NREL 3
#define NEG 0.2f
#define MAXDEG 128   // max in-degree; E=160k over N=10k dst -> Binomial mean 16, max ~45. 128 is hugely safe.

typedef float vfloat4 __attribute__((ext_vector_type(4)));  // native vec for nontemporal builtins

__device__ __forceinline__ float warp32_reduce(float p) {
#pragma unroll
    for (int off = 16; off > 0; off >>= 1) p += __shfl_down(p, off, 32);
    return p;
}

// ---- CSR build -------------------------------------------------------------

__global__ void k_init(int* deg, int* fill, float* pools, float* cnt, int nnodes, int ngraph) {
    int i = blockIdx.x * blockDim.x + threadIdx.x;
    if (i < nnodes) { deg[i] = 0; fill[i] = 0; }
    if (i < ngraph * HEADS) pools[i] = 0.f;
    if (i < ngraph) cnt[i] = 0.f;
}

__global__ void k_deg(const int* __restrict__ ei, int* deg, int nedges) {
    int e = blockIdx.x * blockDim.x + threadIdx.x;
    if (e < nedges) atomicAdd(&deg[ei[nedges + e]], 1);
}

// single-block exclusive scan over nnodes degrees -> rowptr[n+1]
__global__ void k_scan(const int* __restrict__ deg, int* rowptr, int n) {
    __shared__ int ss[1024];
    int tid = threadIdx.x;
    int per = (n + 1023) >> 10;
    int b = tid * per;
    int s = 0;
    for (int i = 0; i < per; i++) { int idx = b + i; if (idx < n) s += deg[idx]; }
    ss[tid] = s;
    __syncthreads();
    for (int off = 1; off < 1024; off <<= 1) {
        int v = (tid >= off) ? ss[tid - off] : 0;
        __syncthreads();
        ss[tid] += v;
        __syncthreads();
    }
    int run = (tid == 0) ? 0 : ss[tid - 1];
    for (int i = 0; i < per; i++) {
        int idx = b + i;
        if (idx < n) { rowptr[idx] = run; run += deg[idx]; }
    }
    if (tid == 0) rowptr[n] = ss[1023];
}

__global__ void k_scatter(const int* __restrict__ ei, const int* __restrict__ et,
                          const float* __restrict__ ea, const int* __restrict__ rowptr,
                          int* fill, int* csr_pack, float* csr_ae, int nedges) {
    int e = blockIdx.x * blockDim.x + threadIdx.x;
    if (e >= nedges) return;
    int dst = ei[nedges + e];
    int pos = atomicAdd(&fill[dst], 1);
    int slot = rowptr[dst] + pos;
    csr_pack[slot] = (ei[e] << 2) | (et[e] & 3);
    csr_ae[slot] = ea[e];
}

// ---- per-layer small precompute: wq[r,i,h]=w[r,i,:]@q[:,h], wk likewise; wee[h]=we@e ----
__global__ void k_prep(const float* __restrict__ w, const float* __restrict__ q,
                       const float* __restrict__ kk, const float* __restrict__ e,
                       const float* __restrict__ we, float* wq, float* wk, float* wee) {
    int tid = threadIdx.x;
    int ri = blockIdx.x;  // r*IN + i
    int h = tid >> 5, lane = tid & 31;
    const float* wrow = w + (size_t)ri * HC;
    float p = 0.f;
    for (int o = lane; o < HC; o += 32) p += wrow[o] * q[o * HEADS + h];
    p = warp32_reduce(p);
    if (lane == 0) wq[ri * HEADS + h] = p;
    p = 0.f;
    for (int o = lane; o < HC; o += 32) p += wrow[o] * kk[o * HEADS + h];
    p = warp32_reduce(p);
    if (lane == 0) wk[ri * HEADS + h] = p;
    if (blockIdx.x == 0 && tid < HEADS) {
        float s = 0.f;
        for (int o = 0; o < HC; o++) s += we[o] * e[o * HEADS + tid];
        wee[tid] = s;
    }
}

// ---- per-node qdot/kdot: qdot[n,r,h] = x[n,:] @ wq[r,:,h]  (48 outputs per node) ----
template <int IN>
__global__ void k_qk(const float* __restrict__ xin, const float* __restrict__ wq,
                     const float* __restrict__ wk, float* __restrict__ qdot,
                     float* __restrict__ kdot, int nnodes) {
    __shared__ float xrow[IN];
    int n = blockIdx.x;
    int tid = threadIdx.x;
    if (tid < IN) xrow[tid] = xin[(size_t)n * IN + tid];
    __syncthreads();
    int g = tid >> 5, lane = tid & 31;
#pragma unroll
    for (int it = 0; it < 6; ++it) {
        int idx = g + 8 * it;          // 0..47
        int qk = idx / 24, rem = idx % 24;
        int r = rem >> 3, h = rem & 7;
        const float* tab = qk ? wk : wq;
        float p = 0.f;
        for (int i = lane; i < IN; i += 32) p += xrow[i] * tab[(r * IN + i) * HEADS + h];
        p = warp32_reduce(p);
        if (lane == 0) (qk ? kdot : qdot)[n * 24 + rem] = p;
    }
}

// ---- tiled fp32 GEMM: xw[n,r,:] = x[n,:] @ w[r]  -------------------------
// 128x128 tile, BK=32, 8x8 micro-tile per thread (256 threads).
// W stays L2-resident (one LDS-staged pass per block); xw written nontemporal
// so the streaming output doesn't wash L2 and evict W.
template <int K>
__global__ __launch_bounds__(256, 2) void k_gemm(const float* __restrict__ xin,
                                                 const float* __restrict__ w,
                                                 float* __restrict__ xw, int nnodes) {
    constexpr int BM = 128, BN = 128, BK = 32;
    __shared__ float xs[BK][BM];   // transposed x tile: xs[k][m]
    __shared__ float wt[BK][BN];   // w tile: wt[k][c]
    int r = blockIdx.z;
    int n0 = blockIdx.x * BM;
    int c1 = blockIdx.y * BN;
    int t = threadIdx.x;
    int tx = t & 15, ty = t >> 4;
    int m0 = ty * 8, c0 = tx * 8;
    float acc[8][8];
#pragma unroll
    for (int i = 0; i < 8; i++)
#pragma unroll
        for (int j = 0; j < 8; j++) acc[i][j] = 0.f;
    const float* wr = w + (size_t)r * K * HC;
    int sm = t >> 1;              // x staging: node within tile
    int skq = (t & 1) * 16;       // x staging: k offset (16 floats = 4 float4)
    int swk = t >> 3;             // w staging: k row
    int swc = (t & 7) * 16;       // w staging: col offset

    for (int k0 = 0; k0 < K; k0 += BK) {
        int gn = n0 + sm;
        const float* xrow = xin + (size_t)gn * K + k0 + skq;
#pragma unroll
        for (int j = 0; j < 4; ++j) {
            float4 v = (gn < nnodes) ? *(const float4*)(xrow + 4 * j)
                                     : make_float4(0.f, 0.f, 0.f, 0.f);
            xs[skq + 4 * j + 0][sm] = v.x;
            xs[skq + 4 * j + 1][sm] = v.y;
            xs[skq + 4 * j + 2][sm] = v.z;
            xs[skq + 4 * j + 3][sm] = v.w;
        }
        const float* wrow = wr + (size_t)(k0 + swk) * HC + c1 + swc;
#pragma unroll
        for (int j = 0; j < 4; ++j) {
            *(float4*)&wt[swk][swc + 4 * j] = *(const float4*)(wrow + 4 * j);
        }
        __syncthreads();
#pragma unroll
        for (int kk = 0; kk < BK; ++kk) {
            float4 a0 = *(const float4*)&xs[kk][m0];
            float4 a1 = *(const float4*)&xs[kk][m0 + 4];
            float4 b0 = *(const float4*)&wt[kk][c0];
            float4 b1 = *(const float4*)&wt[kk][c0 + 4];
            float am[8] = {a0.x, a0.y, a0.z, a0.w, a1.x, a1.y, a1.z, a1.w};
            float bn[8] = {b0.x, b0.y, b0.z, b0.w, b1.x, b1.y, b1.z, b1.w};
#pragma unroll
            for (int i = 0; i < 8; i++)
#pragma unroll
                for (int j = 0; j < 8; j++) acc[i][j] += am[i] * bn[j];
        }
        __syncthreads();
    }
#pragma unroll
    for (int i = 0; i < 8; ++i) {
        int n = n0 + m0 + i;
        if (n < nnodes) {
            float* dst = xw + ((size_t)n * NREL + r) * HC + c1 + c0;
            vfloat4 v0 = {acc[i][0], acc[i][1], acc[i][2], acc[i][3]};
            vfloat4 v1 = {acc[i][4], acc[i][5], acc[i][6], acc[i][7]};
            __builtin_nontemporal_store(v0, (vfloat4*)dst);
            __builtin_nontemporal_store(v1, (vfloat4*)(dst + 4));
        }
    }
}

// ---- per-dst-node attention softmax + aggregation + bias + relu ----
__global__ void k_agg(const float* __restrict__ xw, const float* __restrict__ qdot,
                      const float* __restrict__ kdot, const int* __restrict__ rowptr,
                      const int* __restrict__ csr_pack, const float* __restrict__ csr_ae,
                      const float* __restrict__ wee, const float* __restrict__ bias,
                      float* __restrict__ hout, int nnodes) {
    __shared__ float salpha[MAXDEG * HEADS];
    __shared__ int spack[MAXDEG];
    __shared__ float sqd[NREL * HEADS];
    __shared__ float sinv[HEADS];
    __shared__ float swee[HEADS];
    int n = blockIdx.x;
    int tid = threadIdx.x;
    int beg = rowptr[n];
    int deg = rowptr[n + 1] - beg;
    if (deg > MAXDEG) deg = MAXDEG;
    if (tid < NREL * HEADS) sqd[tid] = qdot[n * 24 + tid];
    if (tid < HEADS) swee[tid] = wee[tid];
    __syncthreads();
    for (int base = 0; base < deg; base += 32) {
        int d = base + (tid >> 3);
        int h = tid & 7;
        if (d < deg) {
            int pk = csr_pack[beg + d];
            float ae = csr_ae[beg + d];
            int s = pk >> 2, t = pk & 3;
            if (h == 0) spack[d] = pk;
            float a = sqd[t * 8 + h] + kdot[s * 24 + t * 8 + h] + ae * swee[h];
            salpha[d * 8 + h] = (a > 0.f) ? a : NEG * a;
        }
    }
    __syncthreads();
    if (tid < HEADS) {
        int h = tid;
        float m = -INFINITY;
        for (int d = 0; d < deg; d++) m = fmaxf(m, salpha[d * 8 + h]);
        float s = 0.f;
        for (int d = 0; d < deg; d++) {
            float ex = expf(salpha[d * 8 + h] - m);
            salpha[d * 8 + h] = ex;
            s += ex;
        }
        sinv[h] = 1.f / (s + 1e-16f);
    }
    __syncthreads();
    int h = tid >> 5;
    float acc = 0.f;
    for (int d = 0; d < deg; ++d) {
        int pk = spack[d];
        int s = pk >> 2, t = pk & 3;
        acc += salpha[d * 8 + h] * xw[((size_t)s * NREL + t) * HC + tid];
    }
    acc *= sinv[h];
    float v = acc + bias[tid];
    hout[(size_t)n * HC + tid] = (v > 0.f) ? v : 0.f;
}

// ---- final linear + tanh + mean-pool ----
__global__ void k_pool(const float* __restrict__ h3, const float* __restrict__ wlin,
                       const float* __restrict__ blin, const int* __restrict__ batch,
                       float* pools, float* cnt, int nnodes) {
    __shared__ float xrow[HC];
    int n = blockIdx.x, tid = threadIdx.x;
    xrow[tid] = h3[(size_t)n * HC + tid];
    __syncthreads();
    int g = tid >> 5, lane = tid & 31;
    float p = 0.f;
    for (int i = lane; i < HC; i += 32) p += xrow[i] * wlin[i * HEADS + g];
    p = warp32_reduce(p);
    int b = batch[n];
    if (lane == 0) atomicAdd(&pools[b * HEADS + g], tanhf(p + blin[g]));
    if (tid == 0) atomicAdd(&cnt[b], 1.f);
}

__global__ void k_div(const float* __restrict__ pools, const float* __restrict__ cnt,
                      float* __restrict__ out, int ngraph) {
    int t = threadIdx.x;
    if (t < ngraph * HEADS) out[t] = pools[t] / fmaxf(cnt[t >> 3], 1.f);
}

// ---------------------------------------------------------------------------

extern "C" void kernel_launch(void* const* d_in, const int* in_sizes, int n_in,
                              void* d_out, int out_size, void* d_ws, size_t ws_size,
                              hipStream_t stream) {
    const float* x    = (const float*)d_in[0];
    const int*   ei   = (const int*)d_in[1];
    const int*   et   = (const int*)d_in[2];
    const float* ea   = (const float*)d_in[3];
    const int*   batch = (const int*)d_in[4];
    const float* W[3]  = {(const float*)d_in[5],  (const float*)d_in[11], (const float*)d_in[17]};
    const float* Q[3]  = {(const float*)d_in[6],  (const float*)d_in[12], (const float*)d_in[18]};
    const float* K[3]  = {(const float*)d_in[7],  (const float*)d_in[13], (const float*)d_in[19]};
    const float* Em[3] = {(const float*)d_in[8],  (const float*)d_in[14], (const float*)d_in[20]};
    const float* WE[3] = {(const float*)d_in[9],  (const float*)d_in[15], (const float*)d_in[21]};
    const float* B[3]  = {(const float*)d_in[10], (const float*)d_in[16], (const float*)d_in[22]};
    const float* wlin = (const float*)d_in[23];
    const float* blin = (const float*)d_in[24];

    int nnodes = in_sizes[0] / 32;
    int nedges = in_sizes[2];
    int ngraph = 16;

    char* ws = (char*)d_ws;
    size_t off = 0;
    auto alloc = [&](size_t bytes) -> void* {
        void* p = ws + off;
        off = (off + bytes + 255) & ~(size_t)255;
        return p;
    };
    int*   deg      = (int*)alloc((size_t)nnodes * 4);
    int*   fill     = (int*)alloc((size_t)nnodes * 4);
    int*   rowptr   = (int*)alloc((size_t)(nnodes + 1) * 4);
    int*   csr_pack = (int*)alloc((size_t)nedges * 4);
    float* csr_ae   = (float*)alloc((size_t)nedges * 4);
    float* xw       = (float*)alloc((size_t)nnodes * NREL * HC * 4);
    float* qdot     = (float*)alloc((size_t)nnodes * NREL * HEADS * 4);
    float* kdot     = (float*)alloc((size_t)nnodes * NREL * HEADS * 4);
    float* ha       = (float*)alloc((size_t)nnodes * HC * 4);
    float* hb       = (float*)alloc((size_t)nnodes * HC * 4);
    float* wq       = (float*)alloc((size_t)NREL * HC * HEADS * 4);
    float* wk       = (float*)alloc((size_t)NREL * HC * HEADS * 4);
    float* wee      = (float*)alloc((size_t)HEADS * 4);
    float* pools    = (float*)alloc((size_t)ngraph * HEADS * 4);
    float* cnt      = (float*)alloc((size_t)ngraph * 4);
    (void)ws_size; (void)n_in; (void)out_size;

    // CSR build (edges are fixed across layers)
    k_init<<<(nnodes + 255) / 256, 256, 0, stream>>>(deg, fill, pools, cnt, nnodes, ngraph);
    k_deg<<<(nedges + 255) / 256, 256, 0, stream>>>(ei, deg, nedges);
    k_scan<<<1, 1024, 0, stream>>>(deg, rowptr, nnodes);
    k_scatter<<<(nedges + 255) / 256, 256, 0, stream>>>(ei, et, ea, rowptr, fill, csr_pack, csr_ae, nedges);

    dim3 ggemm((nnodes + 127) / 128, HC / 128, NREL);

    // ---- layer 1 (IN=32): x -> ha ----
    k_prep<<<NREL * 32, 256, 0, stream>>>(W[0], Q[0], K[0], Em[0], WE[0], wq, wk, wee);
    k_qk<32><<<nnodes, 256, 0, stream>>>(x, wq, wk, qdot, kdot, nnodes);
    k_gemm<32><<<ggemm, 256, 0, stream>>>(x, W[0], xw, nnodes);
    k_agg<<<nnodes, 256, 0, stream>>>(xw, qdot, kdot, rowptr, csr_pack, csr_ae, wee, B[0], ha, nnodes);

    // ---- layer 2 (IN=256): ha -> hb ----
    k_prep<<<NREL * HC, 256, 0, stream>>>(W[1], Q[1], K[1], Em[1], WE[1], wq, wk, wee);
    k_qk<HC><<<nnodes, 256, 0, stream>>>(ha, wq, wk, qdot, kdot, nnodes);
    k_gemm<HC><<<ggemm, 256, 0, stream>>>(ha, W[1], xw, nnodes);
    k_agg<<<nnodes, 256, 0, stream>>>(xw, qdot, kdot, rowptr, csr_pack, csr_ae, wee, B[1], hb, nnodes);

    // ---- layer 3 (IN=256): hb -> ha ----
    k_prep<<<NREL * HC, 256, 0, stream>>>(W[2], Q[2], K[2], Em[2], WE[2], wq, wk, wee);
    k_qk<HC><<<nnodes, 256, 0, stream>>>(hb, wq, wk, qdot, kdot, nnodes);
    k_gemm<HC><<<ggemm, 256, 0, stream>>>(hb, W[2], xw, nnodes);
    k_agg<<<nnodes, 256, 0, stream>>>(xw, qdot, kdot, rowptr, csr_pack, csr_ae, wee, B[2], ha, nnodes);

    // ---- head: linear + tanh + mean pool ----
    k_pool<<<nnodes, 256, 0, stream>>>(ha, wlin, blin, batch, pools, cnt, nnodes);
    k_div<<<1, 128, 0, stream>>>(pools, cnt, (float*)d_out, ngraph);
}

// Round 4
// 940.468 us; speedup vs baseline: 1.5944x; 1.3573x over previous
//
#include <hip/hip_runtime.h>
#include <math.h>

#define HEADS 8
#define HC 256
#define NREL 3
#define NEG 0.2f
#define MAXDEG 128   // max in-degree; E=160k over N=10k dst -> mean 16, max ~45. 128 is hugely safe.

typedef float vfloat4 __attribute__((ext_vector_type(4)));  // native vec for nontemporal builtins

__device__ __forceinline__ float warp32_reduce(float p) {
#pragma unroll
    for (int off = 16; off > 0; off >>= 1) p += __shfl_down(p, off, 32);
    return p;
}

// ---- CSR build -------------------------------------------------------------

__global__ void k_init(int* deg, int* fill, float* pools, float* cnt, int nnodes, int ngraph) {
    int i = blockIdx.x * blockDim.x + threadIdx.x;
    if (i < nnodes) { deg[i] = 0; fill[i] = 0; }
    if (i < ngraph * HEADS) pools[i] = 0.f;
    if (i < ngraph) cnt[i] = 0.f;
}

__global__ void k_deg(const int* __restrict__ ei, int* deg, int nedges) {
    int e = blockIdx.x * blockDim.x + threadIdx.x;
    if (e < nedges) atomicAdd(&deg[ei[nedges + e]], 1);
}

// single-block exclusive scan over nnodes degrees -> rowptr[n+1]
__global__ void k_scan(const int* __restrict__ deg, int* rowptr, int n) {
    __shared__ int ss[1024];
    int tid = threadIdx.x;
    int per = (n + 1023) >> 10;
    int b = tid * per;
    int s = 0;
    for (int i = 0; i < per; i++) { int idx = b + i; if (idx < n) s += deg[idx]; }
    ss[tid] = s;
    __syncthreads();
    for (int off = 1; off < 1024; off <<= 1) {
        int v = (tid >= off) ? ss[tid - off] : 0;
        __syncthreads();
        ss[tid] += v;
        __syncthreads();
    }
    int run = (tid == 0) ? 0 : ss[tid - 1];
    for (int i = 0; i < per; i++) {
        int idx = b + i;
        if (idx < n) { rowptr[idx] = run; run += deg[idx]; }
    }
    if (tid == 0) rowptr[n] = ss[1023];
}

__global__ void k_scatter(const int* __restrict__ ei, const int* __restrict__ et,
                          const float* __restrict__ ea, const int* __restrict__ rowptr,
                          int* fill, int* csr_pack, float* csr_ae, int nedges) {
    int e = blockIdx.x * blockDim.x + threadIdx.x;
    if (e >= nedges) return;
    int dst = ei[nedges + e];
    int pos = atomicAdd(&fill[dst], 1);
    int slot = rowptr[dst] + pos;
    csr_pack[slot] = (ei[e] << 2) | (et[e] & 3);
    csr_ae[slot] = ea[e];
}

// ---- per-layer small precompute --------------------------------------------
// wqk[i][r*8+h]      = w[r,i,:] @ q[:,h]   (cols 0..23)
// wqk[i][24+r*8+h]   = w[r,i,:] @ k[:,h]   (cols 24..47)
// wee[h]             = we @ e[:,h]
__global__ void k_prep(const float* __restrict__ w, const float* __restrict__ q,
                       const float* __restrict__ kk, const float* __restrict__ e,
                       const float* __restrict__ we, float* wqk, float* wee, int IN) {
    int tid = threadIdx.x;
    int ri = blockIdx.x;  // r*IN + i
    int r = ri / IN, i = ri % IN;
    int h = tid >> 5, lane = tid & 31;
    const float* wrow = w + (size_t)ri * HC;
    float p = 0.f;
    for (int o = lane; o < HC; o += 32) p += wrow[o] * q[o * HEADS + h];
    p = warp32_reduce(p);
    if (lane == 0) wqk[i * 48 + r * 8 + h] = p;
    p = 0.f;
    for (int o = lane; o < HC; o += 32) p += wrow[o] * kk[o * HEADS + h];
    p = warp32_reduce(p);
    if (lane == 0) wqk[i * 48 + 24 + r * 8 + h] = p;
    if (blockIdx.x == 0 && tid < HEADS) {
        float s = 0.f;
        for (int o = 0; o < HC; o++) s += we[o] * e[o * HEADS + tid];
        wee[tid] = s;
    }
}

// ---- skinny GEMM for qdot/kdot: [nnodes x K] @ [K x 48] --------------------
// BM=128 nodes, BN=48 cols, BK=32; 256 threads, 8x3 micro-tile each.
template <int K>
__global__ __launch_bounds__(256) void k_qk(const float* __restrict__ xin,
                                            const float* __restrict__ wqk,
                                            float* __restrict__ qdot,
                                            float* __restrict__ kdot, int nnodes) {
    constexpr int BM = 128, BK = 32;
    __shared__ float xs[BK][BM];   // transposed x tile
    __shared__ float wt[BK][48];
    int n0 = blockIdx.x * BM;
    int t = threadIdx.x;
    int tx = t & 15, ty = t >> 4;
    int m0 = ty * 8, c0 = tx * 3;
    float acc[8][3];
#pragma unroll
    for (int i = 0; i < 8; i++)
#pragma unroll
        for (int j = 0; j < 3; j++) acc[i][j] = 0.f;
    int sm = t >> 1;
    int skq = (t & 1) * 16;
    for (int k0 = 0; k0 < K; k0 += BK) {
        int gn = n0 + sm;
        const float* xrow = xin + (size_t)gn * K + k0 + skq;
#pragma unroll
        for (int j = 0; j < 4; ++j) {
            float4 v = (gn < nnodes) ? *(const float4*)(xrow + 4 * j)
                                     : make_float4(0.f, 0.f, 0.f, 0.f);
            xs[skq + 4 * j + 0][sm] = v.x;
            xs[skq + 4 * j + 1][sm] = v.y;
            xs[skq + 4 * j + 2][sm] = v.z;
            xs[skq + 4 * j + 3][sm] = v.w;
        }
        for (int idx = t; idx < BK * 48; idx += 256) {
            int kk = idx / 48, c = idx % 48;
            wt[kk][c] = wqk[(size_t)(k0 + kk) * 48 + c];
        }
        __syncthreads();
#pragma unroll
        for (int kk = 0; kk < BK; ++kk) {
            float b0 = wt[kk][c0], b1 = wt[kk][c0 + 1], b2 = wt[kk][c0 + 2];
            float4 a0 = *(const float4*)&xs[kk][m0];
            float4 a1 = *(const float4*)&xs[kk][m0 + 4];
            float am[8] = {a0.x, a0.y, a0.z, a0.w, a1.x, a1.y, a1.z, a1.w};
#pragma unroll
            for (int i = 0; i < 8; i++) {
                acc[i][0] += am[i] * b0;
                acc[i][1] += am[i] * b1;
                acc[i][2] += am[i] * b2;
            }
        }
        __syncthreads();
    }
#pragma unroll
    for (int i = 0; i < 8; ++i) {
        int n = n0 + m0 + i;
        if (n < nnodes) {
#pragma unroll
            for (int j = 0; j < 3; ++j) {
                int c = c0 + j;
                if (c < 24) qdot[n * 24 + c] = acc[i][j];
                else        kdot[n * 24 + (c - 24)] = acc[i][j];
            }
        }
    }
}

// ---- tiled fp32 GEMM: xw[n,r,:] = x[n,:] @ w[r]  -------------------------
template <int K>
__global__ __launch_bounds__(256, 2) void k_gemm(const float* __restrict__ xin,
                                                 const float* __restrict__ w,
                                                 float* __restrict__ xw, int nnodes) {
    constexpr int BM = 128, BN = 128, BK = 32;
    __shared__ float xs[BK][BM];   // transposed x tile: xs[k][m]
    __shared__ float wt[BK][BN];   // w tile: wt[k][c]
    int r = blockIdx.z;
    int n0 = blockIdx.x * BM;
    int c1 = blockIdx.y * BN;
    int t = threadIdx.x;
    int tx = t & 15, ty = t >> 4;
    int m0 = ty * 8, c0 = tx * 8;
    float acc[8][8];
#pragma unroll
    for (int i = 0; i < 8; i++)
#pragma unroll
        for (int j = 0; j < 8; j++) acc[i][j] = 0.f;
    const float* wr = w + (size_t)r * K * HC;
    int sm = t >> 1;              // x staging: node within tile
    int skq = (t & 1) * 16;       // x staging: k offset (16 floats = 4 float4)
    int swk = t >> 3;             // w staging: k row
    int swc = (t & 7) * 16;       // w staging: col offset

    for (int k0 = 0; k0 < K; k0 += BK) {
        int gn = n0 + sm;
        const float* xrow = xin + (size_t)gn * K + k0 + skq;
#pragma unroll
        for (int j = 0; j < 4; ++j) {
            float4 v = (gn < nnodes) ? *(const float4*)(xrow + 4 * j)
                                     : make_float4(0.f, 0.f, 0.f, 0.f);
            xs[skq + 4 * j + 0][sm] = v.x;
            xs[skq + 4 * j + 1][sm] = v.y;
            xs[skq + 4 * j + 2][sm] = v.z;
            xs[skq + 4 * j + 3][sm] = v.w;
        }
        const float* wrow = wr + (size_t)(k0 + swk) * HC + c1 + swc;
#pragma unroll
        for (int j = 0; j < 4; ++j) {
            *(float4*)&wt[swk][swc + 4 * j] = *(const float4*)(wrow + 4 * j);
        }
        __syncthreads();
#pragma unroll
        for (int kk = 0; kk < BK; ++kk) {
            float4 a0 = *(const float4*)&xs[kk][m0];
            float4 a1 = *(const float4*)&xs[kk][m0 + 4];
            float4 b0 = *(const float4*)&wt[kk][c0];
            float4 b1 = *(const float4*)&wt[kk][c0 + 4];
            float am[8] = {a0.x, a0.y, a0.z, a0.w, a1.x, a1.y, a1.z, a1.w};
            float bn[8] = {b0.x, b0.y, b0.z, b0.w, b1.x, b1.y, b1.z, b1.w};
#pragma unroll
            for (int i = 0; i < 8; i++)
#pragma unroll
                for (int j = 0; j < 8; j++) acc[i][j] += am[i] * bn[j];
        }
        __syncthreads();
    }
#pragma unroll
    for (int i = 0; i < 8; ++i) {
        int n = n0 + m0 + i;
        if (n < nnodes) {
            float* dst = xw + ((size_t)n * NREL + r) * HC + c1 + c0;
            vfloat4 v0 = {acc[i][0], acc[i][1], acc[i][2], acc[i][3]};
            vfloat4 v1 = {acc[i][4], acc[i][5], acc[i][6], acc[i][7]};
            __builtin_nontemporal_store(v0, (vfloat4*)dst);
            __builtin_nontemporal_store(v1, (vfloat4*)(dst + 4));
        }
    }
}

// ---- per-dst-node attention softmax + aggregation + bias + relu ----
__global__ void k_agg(const float* __restrict__ xw, const float* __restrict__ qdot,
                      const float* __restrict__ kdot, const int* __restrict__ rowptr,
                      const int* __restrict__ csr_pack, const float* __restrict__ csr_ae,
                      const float* __restrict__ wee, const float* __restrict__ bias,
                      float* __restrict__ hout, int nnodes) {
    __shared__ float salpha[MAXDEG * HEADS];
    __shared__ int spack[MAXDEG];
    __shared__ float sqd[NREL * HEADS];
    __shared__ float sinv[HEADS];
    __shared__ float swee[HEADS];
    int n = blockIdx.x;
    int tid = threadIdx.x;
    int beg = rowptr[n];
    int deg = rowptr[n + 1] - beg;
    if (deg > MAXDEG) deg = MAXDEG;
    if (tid < NREL * HEADS) sqd[tid] = qdot[n * 24 + tid];
    if (tid < HEADS) swee[tid] = wee[tid];
    __syncthreads();
    for (int base = 0; base < deg; base += 32) {
        int d = base + (tid >> 3);
        int h = tid & 7;
        if (d < deg) {
            int pk = csr_pack[beg + d];
            float ae = csr_ae[beg + d];
            int s = pk >> 2, t = pk & 3;
            if (h == 0) spack[d] = pk;
            float a = sqd[t * 8 + h] + kdot[s * 24 + t * 8 + h] + ae * swee[h];
            salpha[d * 8 + h] = (a > 0.f) ? a : NEG * a;
        }
    }
    __syncthreads();
    if (tid < HEADS) {
        int h = tid;
        float m = -INFINITY;
        for (int d = 0; d < deg; d++) m = fmaxf(m, salpha[d * 8 + h]);
        float s = 0.f;
        for (int d = 0; d < deg; d++) {
            float ex = expf(salpha[d * 8 + h] - m);
            salpha[d * 8 + h] = ex;
            s += ex;
        }
        sinv[h] = 1.f / (s + 1e-16f);
    }
    __syncthreads();
    int h = tid >> 5;
    float acc = 0.f;
    for (int d = 0; d < deg; ++d) {
        int pk = spack[d];
        int s = pk >> 2, t = pk & 3;
        acc += salpha[d * 8 + h] * xw[((size_t)s * NREL + t) * HC + tid];
    }
    acc *= sinv[h];
    float v = acc + bias[tid];
    hout[(size_t)n * HC + tid] = (v > 0.f) ? v : 0.f;
}

// ---- final linear + tanh + mean-pool ----
__global__ void k_pool(const float* __restrict__ h3, const float* __restrict__ wlin,
                       const float* __restrict__ blin, const int* __restrict__ batch,
                       float* pools, float* cnt, int nnodes) {
    __shared__ float xrow[HC];
    int n = blockIdx.x, tid = threadIdx.x;
    xrow[tid] = h3[(size_t)n * HC + tid];
    __syncthreads();
    int g = tid >> 5, lane = tid & 31;
    float p = 0.f;
    for (int i = lane; i < HC; i += 32) p += xrow[i] * wlin[i * HEADS + g];
    p = warp32_reduce(p);
    int b = batch[n];
    if (lane == 0) atomicAdd(&pools[b * HEADS + g], tanhf(p + blin[g]));
    if (tid == 0) atomicAdd(&cnt[b], 1.f);
}

__global__ void k_div(const float* __restrict__ pools, const float* __restrict__ cnt,
                      float* __restrict__ out, int ngraph) {
    int t = threadIdx.x;
    if (t < ngraph * HEADS) out[t] = pools[t] / fmaxf(cnt[t >> 3], 1.f);
}

// ---------------------------------------------------------------------------

extern "C" void kernel_launch(void* const* d_in, const int* in_sizes, int n_in,
                              void* d_out, int out_size, void* d_ws, size_t ws_size,
                              hipStream_t stream) {
    const float* x    = (const float*)d_in[0];
    const int*   ei   = (const int*)d_in[1];
    const int*   et   = (const int*)d_in[2];
    const float* ea   = (const float*)d_in[3];
    const int*   batch = (const int*)d_in[4];
    const float* W[3]  = {(const float*)d_in[5],  (const float*)d_in[11], (const float*)d_in[17]};
    const float* Q[3]  = {(const float*)d_in[6],  (const float*)d_in[12], (const float*)d_in[18]};
    const float* K[3]  = {(const float*)d_in[7],  (const float*)d_in[13], (const float*)d_in[19]};
    const float* Em[3] = {(const float*)d_in[8],  (const float*)d_in[14], (const float*)d_in[20]};
    const float* WE[3] = {(const float*)d_in[9],  (const float*)d_in[15], (const float*)d_in[21]};
    const float* B[3]  = {(const float*)d_in[10], (const float*)d_in[16], (const float*)d_in[22]};
    const float* wlin = (const float*)d_in[23];
    const float* blin = (const float*)d_in[24];

    int nnodes = in_sizes[0] / 32;
    int nedges = in_sizes[2];
    int ngraph = 16;

    char* ws = (char*)d_ws;
    size_t off = 0;
    auto alloc = [&](size_t bytes) -> void* {
        void* p = ws + off;
        off = (off + bytes + 255) & ~(size_t)255;
        return p;
    };
    int*   deg      = (int*)alloc((size_t)nnodes * 4);
    int*   fill     = (int*)alloc((size_t)nnodes * 4);
    int*   rowptr   = (int*)alloc((size_t)(nnodes + 1) * 4);
    int*   csr_pack = (int*)alloc((size_t)nedges * 4);
    float* csr_ae   = (float*)alloc((size_t)nedges * 4);
    float* xw       = (float*)alloc((size_t)nnodes * NREL * HC * 4);
    float* qdot     = (float*)alloc((size_t)nnodes * NREL * HEADS * 4);
    float* kdot     = (float*)alloc((size_t)nnodes * NREL * HEADS * 4);
    float* ha       = (float*)alloc((size_t)nnodes * HC * 4);
    float* hb       = (float*)alloc((size_t)nnodes * HC * 4);
    float* wqk      = (float*)alloc((size_t)HC * 48 * 4);
    float* wee      = (float*)alloc((size_t)HEADS * 4);
    float* pools    = (float*)alloc((size_t)ngraph * HEADS * 4);
    float* cnt      = (float*)alloc((size_t)ngraph * 4);
    (void)ws_size; (void)n_in; (void)out_size;

    // CSR build (edges are fixed across layers)
    k_init<<<(nnodes + 255) / 256, 256, 0, stream>>>(deg, fill, pools, cnt, nnodes, ngraph);
    k_deg<<<(nedges + 255) / 256, 256, 0, stream>>>(ei, deg, nedges);
    k_scan<<<1, 1024, 0, stream>>>(deg, rowptr, nnodes);
    k_scatter<<<(nedges + 255) / 256, 256, 0, stream>>>(ei, et, ea, rowptr, fill, csr_pack, csr_ae, nedges);

    dim3 ggemm((nnodes + 127) / 128, HC / 128, NREL);
    int gqk = (nnodes + 127) / 128;

    // ---- layer 1 (IN=32): x -> ha ----
    k_prep<<<NREL * 32, 256, 0, stream>>>(W[0], Q[0], K[0], Em[0], WE[0], wqk, wee, 32);
    k_qk<32><<<gqk, 256, 0, stream>>>(x, wqk, qdot, kdot, nnodes);
    k_gemm<32><<<ggemm, 256, 0, stream>>>(x, W[0], xw, nnodes);
    k_agg<<<nnodes, 256, 0, stream>>>(xw, qdot, kdot, rowptr, csr_pack, csr_ae, wee, B[0], ha, nnodes);

    // ---- layer 2 (IN=256): ha -> hb ----
    k_prep<<<NREL * HC, 256, 0, stream>>>(W[1], Q[1], K[1], Em[1], WE[1], wqk, wee, HC);
    k_qk<HC><<<gqk, 256, 0, stream>>>(ha, wqk, qdot, kdot, nnodes);
    k_gemm<HC><<<ggemm, 256, 0, stream>>>(ha, W[1], xw, nnodes);
    k_agg<<<nnodes, 256, 0, stream>>>(xw, qdot, kdot, rowptr, csr_pack, csr_ae, wee, B[1], hb, nnodes);

    // ---- layer 3 (IN=256): hb -> ha ----
    k_prep<<<NREL * HC, 256, 0, stream>>>(W[2], Q[2], K[2], Em[2], WE[2], wqk, wee, HC);
    k_qk<HC><<<gqk, 256, 0, stream>>>(hb, wqk, qdot, kdot, nnodes);
    k_gemm<HC><<<ggemm, 256, 0, stream>>>(hb, W[2], xw, nnodes);
    k_agg<<<nnodes, 256, 0, stream>>>(xw, qdot, kdot, rowptr, csr_pack, csr_ae, wee, B[2], ha, nnodes);

    // ---- head: linear + tanh + mean pool ----
    k_pool<<<nnodes, 256, 0, stream>>>(ha, wlin, blin, batch, pools, cnt, nnodes);
    k_div<<<1, 128, 0, stream>>>(pools, cnt, (float*)d_out, ngraph);
}

// Round 5
// 687.664 us; speedup vs baseline: 2.1806x; 1.3676x over previous
//
#include <hip/hip_runtime.h>
#include <math.h>

#define HEADS 8
#define HC 256
#define NREL 3
#define NEG 0.2f
#define MAXDEG 128   // max in-degree; E=160k over N=10k dst -> mean 16, max ~45. 128 is hugely safe.
#define PCHUNK 8     // chunk-blocks per graph in the pool kernel

typedef float vfloat4 __attribute__((ext_vector_type(4)));  // native vec for nontemporal builtins

__device__ __forceinline__ float warp32_reduce(float p) {
#pragma unroll
    for (int off = 16; off > 0; off >>= 1) p += __shfl_down(p, off, 32);
    return p;
}

// ---- CSR build -------------------------------------------------------------

__global__ void k_init(int* deg, int* fill, int nnodes) {
    int i = blockIdx.x * blockDim.x + threadIdx.x;
    if (i < nnodes) { deg[i] = 0; fill[i] = 0; }
}

__global__ void k_deg(const int* __restrict__ ei, int* deg, int nedges) {
    int e = blockIdx.x * blockDim.x + threadIdx.x;
    if (e < nedges) atomicAdd(&deg[ei[nedges + e]], 1);
}

// single-block exclusive scan over nnodes degrees -> rowptr[n+1]
__global__ void k_scan(const int* __restrict__ deg, int* rowptr, int n) {
    __shared__ int ss[1024];
    int tid = threadIdx.x;
    int per = (n + 1023) >> 10;
    int b = tid * per;
    int s = 0;
    for (int i = 0; i < per; i++) { int idx = b + i; if (idx < n) s += deg[idx]; }
    ss[tid] = s;
    __syncthreads();
    for (int off = 1; off < 1024; off <<= 1) {
        int v = (tid >= off) ? ss[tid - off] : 0;
        __syncthreads();
        ss[tid] += v;
        __syncthreads();
    }
    int run = (tid == 0) ? 0 : ss[tid - 1];
    for (int i = 0; i < per; i++) {
        int idx = b + i;
        if (idx < n) { rowptr[idx] = run; run += deg[idx]; }
    }
    if (tid == 0) rowptr[n] = ss[1023];
}

__global__ void k_scatter(const int* __restrict__ ei, const int* __restrict__ et,
                          const float* __restrict__ ea, const int* __restrict__ rowptr,
                          int* fill, int* csr_pack, float* csr_ae, int nedges) {
    int e = blockIdx.x * blockDim.x + threadIdx.x;
    if (e >= nedges) return;
    int dst = ei[nedges + e];
    int pos = atomicAdd(&fill[dst], 1);
    int slot = rowptr[dst] + pos;
    csr_pack[slot] = (ei[e] << 2) | (et[e] & 3);
    csr_ae[slot] = ea[e];
}

// ---- per-layer small precompute --------------------------------------------
// wqk[i][r*8+h]      = w[r,i,:] @ q[:,h]   (cols 0..23)
// wqk[i][24+r*8+h]   = w[r,i,:] @ k[:,h]   (cols 24..47)
// wee[h]             = we @ e[:,h]
__global__ void k_prep(const float* __restrict__ w, const float* __restrict__ q,
                       const float* __restrict__ kk, const float* __restrict__ e,
                       const float* __restrict__ we, float* wqk, float* wee, int IN) {
    int tid = threadIdx.x;
    int ri = blockIdx.x;  // r*IN + i
    int r = ri / IN, i = ri % IN;
    int h = tid >> 5, lane = tid & 31;
    const float* wrow = w + (size_t)ri * HC;
    float p = 0.f;
    for (int o = lane; o < HC; o += 32) p += wrow[o] * q[o * HEADS + h];
    p = warp32_reduce(p);
    if (lane == 0) wqk[i * 48 + r * 8 + h] = p;
    p = 0.f;
    for (int o = lane; o < HC; o += 32) p += wrow[o] * kk[o * HEADS + h];
    p = warp32_reduce(p);
    if (lane == 0) wqk[i * 48 + 24 + r * 8 + h] = p;
    if (blockIdx.x == 0 && tid < HEADS) {
        float s = 0.f;
        for (int o = 0; o < HC; o++) s += we[o] * e[o * HEADS + tid];
        wee[tid] = s;
    }
}

// ---- skinny GEMM for qdot/kdot: [nnodes x K] @ [K x 48] --------------------
template <int K>
__global__ __launch_bounds__(256) void k_qk(const float* __restrict__ xin,
                                            const float* __restrict__ wqk,
                                            float* __restrict__ qdot,
                                            float* __restrict__ kdot, int nnodes) {
    constexpr int BM = 128, BK = 32;
    __shared__ float xs[BK][BM];   // transposed x tile
    __shared__ float wt[BK][48];
    int n0 = blockIdx.x * BM;
    int t = threadIdx.x;
    int tx = t & 15, ty = t >> 4;
    int m0 = ty * 8, c0 = tx * 3;
    float acc[8][3];
#pragma unroll
    for (int i = 0; i < 8; i++)
#pragma unroll
        for (int j = 0; j < 3; j++) acc[i][j] = 0.f;
    int sm = t >> 1;
    int skq = (t & 1) * 16;
    for (int k0 = 0; k0 < K; k0 += BK) {
        int gn = n0 + sm;
        const float* xrow = xin + (size_t)gn * K + k0 + skq;
#pragma unroll
        for (int j = 0; j < 4; ++j) {
            float4 v = (gn < nnodes) ? *(const float4*)(xrow + 4 * j)
                                     : make_float4(0.f, 0.f, 0.f, 0.f);
            xs[skq + 4 * j + 0][sm] = v.x;
            xs[skq + 4 * j + 1][sm] = v.y;
            xs[skq + 4 * j + 2][sm] = v.z;
            xs[skq + 4 * j + 3][sm] = v.w;
        }
        for (int idx = t; idx < BK * 48; idx += 256) {
            int kk = idx / 48, c = idx % 48;
            wt[kk][c] = wqk[(size_t)(k0 + kk) * 48 + c];
        }
        __syncthreads();
#pragma unroll
        for (int kk = 0; kk < BK; ++kk) {
            float b0 = wt[kk][c0], b1 = wt[kk][c0 + 1], b2 = wt[kk][c0 + 2];
            float4 a0 = *(const float4*)&xs[kk][m0];
            float4 a1 = *(const float4*)&xs[kk][m0 + 4];
            float am[8] = {a0.x, a0.y, a0.z, a0.w, a1.x, a1.y, a1.z, a1.w};
#pragma unroll
            for (int i = 0; i < 8; i++) {
                acc[i][0] += am[i] * b0;
                acc[i][1] += am[i] * b1;
                acc[i][2] += am[i] * b2;
            }
        }
        __syncthreads();
    }
#pragma unroll
    for (int i = 0; i < 8; ++i) {
        int n = n0 + m0 + i;
        if (n < nnodes) {
#pragma unroll
            for (int j = 0; j < 3; ++j) {
                int c = c0 + j;
                if (c < 24) qdot[n * 24 + c] = acc[i][j];
                else        kdot[n * 24 + (c - 24)] = acc[i][j];
            }
        }
    }
}

// ---- tiled fp32 GEMM: xw[n,r,:] = x[n,:] @ w[r]  -------------------------
// 128x128 tile, BK=32. B-fragment = wt[kk][tx*4] and wt[kk][64+tx*4]
// (16 consecutive float4s per 16 lanes -> <=2-way LDS aliasing = free).
template <int K>
__global__ __launch_bounds__(256, 2) void k_gemm(const float* __restrict__ xin,
                                                 const float* __restrict__ w,
                                                 float* __restrict__ xw, int nnodes) {
    constexpr int BM = 128, BN = 128, BK = 32;
    __shared__ float xs[BK][BM];   // transposed x tile: xs[k][m]
    __shared__ float wt[BK][BN];   // w tile: wt[k][c]
    int r = blockIdx.z;
    int n0 = blockIdx.x * BM;
    int c1 = blockIdx.y * BN;
    int t = threadIdx.x;
    int tx = t & 15, ty = t >> 4;
    int m0 = ty * 8;
    int c0a = tx * 4, c0b = 64 + tx * 4;
    float acc[8][8];
#pragma unroll
    for (int i = 0; i < 8; i++)
#pragma unroll
        for (int j = 0; j < 8; j++) acc[i][j] = 0.f;
    const float* wr = w + (size_t)r * K * HC;
    int sm = t >> 1;              // x staging: node within tile
    int skq = (t & 1) * 16;       // x staging: k offset (16 floats = 4 float4)

    for (int k0 = 0; k0 < K; k0 += BK) {
        int gn = n0 + sm;
        const float* xrow = xin + (size_t)gn * K + k0 + skq;
#pragma unroll
        for (int j = 0; j < 4; ++j) {
            float4 v = (gn < nnodes) ? *(const float4*)(xrow + 4 * j)
                                     : make_float4(0.f, 0.f, 0.f, 0.f);
            xs[skq + 4 * j + 0][sm] = v.x;
            xs[skq + 4 * j + 1][sm] = v.y;
            xs[skq + 4 * j + 2][sm] = v.z;
            xs[skq + 4 * j + 3][sm] = v.w;
        }
        // flat coalesced staging of the 32x128 W tile (float4 granularity)
#pragma unroll
        for (int it = 0; it < 4; ++it) {
            int fidx = t + 256 * it;         // 0..1023
            int kk = fidx >> 5;              // /(BN/4)
            int c4 = (fidx & 31) << 2;
            *(float4*)&wt[kk][c4] = *(const float4*)(wr + (size_t)(k0 + kk) * HC + c1 + c4);
        }
        __syncthreads();
#pragma unroll
        for (int kk = 0; kk < BK; ++kk) {
            float4 a0 = *(const float4*)&xs[kk][m0];
            float4 a1 = *(const float4*)&xs[kk][m0 + 4];
            float4 b0 = *(const float4*)&wt[kk][c0a];
            float4 b1 = *(const float4*)&wt[kk][c0b];
            float am[8] = {a0.x, a0.y, a0.z, a0.w, a1.x, a1.y, a1.z, a1.w};
            float bn[8] = {b0.x, b0.y, b0.z, b0.w, b1.x, b1.y, b1.z, b1.w};
#pragma unroll
            for (int i = 0; i < 8; i++)
#pragma unroll
                for (int j = 0; j < 8; j++) acc[i][j] += am[i] * bn[j];
        }
        __syncthreads();
    }
#pragma unroll
    for (int i = 0; i < 8; ++i) {
        int n = n0 + m0 + i;
        if (n < nnodes) {
            float* base = xw + ((size_t)n * NREL + r) * HC + c1;
            vfloat4 v0 = {acc[i][0], acc[i][1], acc[i][2], acc[i][3]};
            vfloat4 v1 = {acc[i][4], acc[i][5], acc[i][6], acc[i][7]};
            __builtin_nontemporal_store(v0, (vfloat4*)(base + c0a));
            __builtin_nontemporal_store(v1, (vfloat4*)(base + c0b));
        }
    }
}

// ---- per-dst-node attention softmax + aggregation + bias + relu ----
__global__ void k_agg(const float* __restrict__ xw, const float* __restrict__ qdot,
                      const float* __restrict__ kdot, const int* __restrict__ rowptr,
                      const int* __restrict__ csr_pack, const float* __restrict__ csr_ae,
                      const float* __restrict__ wee, const float* __restrict__ bias,
                      float* __restrict__ hout, int nnodes) {
    __shared__ float salpha[MAXDEG * HEADS];
    __shared__ int spack[MAXDEG];
    __shared__ float sqd[NREL * HEADS];
    __shared__ float sinv[HEADS];
    __shared__ float swee[HEADS];
    int n = blockIdx.x;
    int tid = threadIdx.x;
    int beg = rowptr[n];
    int deg = rowptr[n + 1] - beg;
    if (deg > MAXDEG) deg = MAXDEG;
    if (tid < NREL * HEADS) sqd[tid] = qdot[n * 24 + tid];
    if (tid < HEADS) swee[tid] = wee[tid];
    __syncthreads();
    for (int base = 0; base < deg; base += 32) {
        int d = base + (tid >> 3);
        int h = tid & 7;
        if (d < deg) {
            int pk = csr_pack[beg + d];
            float ae = csr_ae[beg + d];
            int s = pk >> 2, t = pk & 3;
            if (h == 0) spack[d] = pk;
            float a = sqd[t * 8 + h] + kdot[s * 24 + t * 8 + h] + ae * swee[h];
            salpha[d * 8 + h] = (a > 0.f) ? a : NEG * a;
        }
    }
    __syncthreads();
    if (tid < HEADS) {
        int h = tid;
        float m = -INFINITY;
        for (int d = 0; d < deg; d++) m = fmaxf(m, salpha[d * 8 + h]);
        float s = 0.f;
        for (int d = 0; d < deg; d++) {
            float ex = expf(salpha[d * 8 + h] - m);
            salpha[d * 8 + h] = ex;
            s += ex;
        }
        sinv[h] = 1.f / (s + 1e-16f);
    }
    __syncthreads();
    int h = tid >> 5;
    float acc = 0.f;
    for (int d = 0; d < deg; ++d) {
        int pk = spack[d];
        int s = pk >> 2, t = pk & 3;
        acc += salpha[d * 8 + h] * xw[((size_t)s * NREL + t) * HC + tid];
    }
    acc *= sinv[h];
    float v = acc + bias[tid];
    hout[(size_t)n * HC + tid] = (v > 0.f) ? v : 0.f;
}

// ---- final linear + tanh + mean-pool (atomic-free) -------------------------
// grid = ngraph*PCHUNK blocks. batch is sorted -> graph = contiguous node range
// (binary search). Lane layout: h = lane&7, grp = lane>>3; per-node dot reduced
// with 3 xor-shuffles; per-wave register accumulation; LDS combine; partials out.
__global__ __launch_bounds__(256) void k_pool2(const float* __restrict__ h3,
                                               const float* __restrict__ wlin,
                                               const float* __restrict__ blin,
                                               const int* __restrict__ batch,
                                               float* __restrict__ partials,
                                               int* __restrict__ gcnt, int nnodes) {
    int g = blockIdx.x / PCHUNK, chunk = blockIdx.x % PCHUNK;
    __shared__ int sb[2];
    if (threadIdx.x < 2) {
        int target = g + threadIdx.x;
        int lo = 0, hi = nnodes;
        while (lo < hi) { int mid = (lo + hi) >> 1; if (batch[mid] < target) lo = mid + 1; else hi = mid; }
        sb[threadIdx.x] = lo;
    }
    __syncthreads();
    int beg = sb[0], end = sb[1];
    int t = threadIdx.x;
    int w = t >> 6, lane = t & 63;
    int h = lane & 7, grp = lane >> 3;
    float rw[32];
#pragma unroll
    for (int k = 0; k < 8; ++k)
#pragma unroll
        for (int j = 0; j < 4; ++j)
            rw[k * 4 + j] = wlin[(grp * 4 + j + 32 * k) * HEADS + h];
    float bl = blin[h];
    float acc = 0.f;
    int wg = chunk * 4 + w;   // 0..31
    for (int n = beg + wg; n < end; n += PCHUNK * 4) {
        const float* row = h3 + (size_t)n * HC;
        float dot = 0.f;
#pragma unroll
        for (int k = 0; k < 8; ++k) {
            float4 v = *(const float4*)&row[grp * 4 + 32 * k];
            dot += v.x * rw[k * 4] + v.y * rw[k * 4 + 1] + v.z * rw[k * 4 + 2] + v.w * rw[k * 4 + 3];
        }
        dot += __shfl_xor(dot, 8, 64);
        dot += __shfl_xor(dot, 16, 64);
        dot += __shfl_xor(dot, 32, 64);
        acc += tanhf(dot + bl);
    }
    __shared__ float sacc[4][HEADS];
    if (lane < HEADS) sacc[w][h] = acc;
    __syncthreads();
    if (t < HEADS) {
        float s = sacc[0][t] + sacc[1][t] + sacc[2][t] + sacc[3][t];
        partials[(size_t)blockIdx.x * HEADS + t] = s;
    }
    if (t == 0 && chunk == 0) gcnt[g] = end - beg;
}

__global__ void k_div(const float* __restrict__ partials, const int* __restrict__ gcnt,
                      float* __restrict__ out, int ngraph) {
    int t = threadIdx.x;
    if (t < ngraph * HEADS) {
        int g = t >> 3, h = t & 7;
        float s = 0.f;
        for (int c = 0; c < PCHUNK; ++c) s += partials[(size_t)(g * PCHUNK + c) * HEADS + h];
        out[t] = s / fmaxf((float)gcnt[g], 1.f);
    }
}

// ---------------------------------------------------------------------------

extern "C" void kernel_launch(void* const* d_in, const int* in_sizes, int n_in,
                              void* d_out, int out_size, void* d_ws, size_t ws_size,
                              hipStream_t stream) {
    const float* x    = (const float*)d_in[0];
    const int*   ei   = (const int*)d_in[1];
    const int*   et   = (const int*)d_in[2];
    const float* ea   = (const float*)d_in[3];
    const int*   batch = (const int*)d_in[4];
    const float* W[3]  = {(const float*)d_in[5],  (const float*)d_in[11], (const float*)d_in[17]};
    const float* Q[3]  = {(const float*)d_in[6],  (const float*)d_in[12], (const float*)d_in[18]};
    const float* K[3]  = {(const float*)d_in[7],  (const float*)d_in[13], (const float*)d_in[19]};
    const float* Em[3] = {(const float*)d_in[8],  (const float*)d_in[14], (const float*)d_in[20]};
    const float* WE[3] = {(const float*)d_in[9],  (const float*)d_in[15], (const float*)d_in[21]};
    const float* B[3]  = {(const float*)d_in[10], (const float*)d_in[16], (const float*)d_in[22]};
    const float* wlin = (const float*)d_in[23];
    const float* blin = (const float*)d_in[24];

    int nnodes = in_sizes[0] / 32;
    int nedges = in_sizes[2];
    int ngraph = 16;

    char* ws = (char*)d_ws;
    size_t off = 0;
    auto alloc = [&](size_t bytes) -> void* {
        void* p = ws + off;
        off = (off + bytes + 255) & ~(size_t)255;
        return p;
    };
    int*   deg      = (int*)alloc((size_t)nnodes * 4);
    int*   fill     = (int*)alloc((size_t)nnodes * 4);
    int*   rowptr   = (int*)alloc((size_t)(nnodes + 1) * 4);
    int*   csr_pack = (int*)alloc((size_t)nedges * 4);
    float* csr_ae   = (float*)alloc((size_t)nedges * 4);
    float* xw       = (float*)alloc((size_t)nnodes * NREL * HC * 4);
    float* qdot     = (float*)alloc((size_t)nnodes * NREL * HEADS * 4);
    float* kdot     = (float*)alloc((size_t)nnodes * NREL * HEADS * 4);
    float* ha       = (float*)alloc((size_t)nnodes * HC * 4);
    float* hb       = (float*)alloc((size_t)nnodes * HC * 4);
    float* wqk      = (float*)alloc((size_t)HC * 48 * 4);
    float* wee      = (float*)alloc((size_t)HEADS * 4);
    float* partials = (float*)alloc((size_t)ngraph * PCHUNK * HEADS * 4);
    int*   gcnt     = (int*)alloc((size_t)ngraph * 4);
    (void)ws_size; (void)n_in; (void)out_size;

    // CSR build (edges are fixed across layers)
    k_init<<<(nnodes + 255) / 256, 256, 0, stream>>>(deg, fill, nnodes);
    k_deg<<<(nedges + 255) / 256, 256, 0, stream>>>(ei, deg, nedges);
    k_scan<<<1, 1024, 0, stream>>>(deg, rowptr, nnodes);
    k_scatter<<<(nedges + 255) / 256, 256, 0, stream>>>(ei, et, ea, rowptr, fill, csr_pack, csr_ae, nedges);

    dim3 ggemm((nnodes + 127) / 128, HC / 128, NREL);
    int gqk = (nnodes + 127) / 128;

    // ---- layer 1 (IN=32): x -> ha ----
    k_prep<<<NREL * 32, 256, 0, stream>>>(W[0], Q[0], K[0], Em[0], WE[0], wqk, wee, 32);
    k_qk<32><<<gqk, 256, 0, stream>>>(x, wqk, qdot, kdot, nnodes);
    k_gemm<32><<<ggemm, 256, 0, stream>>>(x, W[0], xw, nnodes);
    k_agg<<<nnodes, 256, 0, stream>>>(xw, qdot, kdot, rowptr, csr_pack, csr_ae, wee, B[0], ha, nnodes);

    // ---- layer 2 (IN=256): ha -> hb ----
    k_prep<<<NREL * HC, 256, 0, stream>>>(W[1], Q[1], K[1], Em[1], WE[1], wqk, wee, HC);
    k_qk<HC><<<gqk, 256, 0, stream>>>(ha, wqk, qdot, kdot, nnodes);
    k_gemm<HC><<<ggemm, 256, 0, stream>>>(ha, W[1], xw, nnodes);
    k_agg<<<nnodes, 256, 0, stream>>>(xw, qdot, kdot, rowptr, csr_pack, csr_ae, wee, B[1], hb, nnodes);

    // ---- layer 3 (IN=256): hb -> ha ----
    k_prep<<<NREL * HC, 256, 0, stream>>>(W[2], Q[2], K[2], Em[2], WE[2], wqk, wee, HC);
    k_qk<HC><<<gqk, 256, 0, stream>>>(hb, wqk, qdot, kdot, nnodes);
    k_gemm<HC><<<ggemm, 256, 0, stream>>>(hb, W[2], xw, nnodes);
    k_agg<<<nnodes, 256, 0, stream>>>(xw, qdot, kdot, rowptr, csr_pack, csr_ae, wee, B[2], ha, nnodes);

    // ---- head: linear + tanh + mean pool (atomic-free) ----
    k_pool2<<<ngraph * PCHUNK, 256, 0, stream>>>(ha, wlin, blin, batch, partials, gcnt, nnodes);
    k_div<<<1, 128, 0, stream>>>(partials, gcnt, (float*)d_out, ngraph);
}